// Round 4
// baseline (105.224 us; speedup 1.0000x reference)
//
#include <hip/hip_runtime.h>

// B=2, HEADS=8, T=8, QH=QW=16, D=64; rows = 32768, K = 2048.
// out[row, k] = scores[row, k] + dotH(qh,kh) + dotW(qw,kw) + dotT(t,kt)
// k = kt*256 + kh*16 + kw; row = (b*H+n)*2048 + t*256 + qh*16 + qw.
//
// v4: one wave per row (4 rows / 256-thread block). Stream iteration i of a
// wave covers exactly kt-block i, so per-lane biases are loop-invariant
// except the kt term: hoist hw4 (=H+W) and tv[0..7] (=T) into registers,
// making the stream loop pure VMEM: 8 loads -> 8 adds -> 8 stores.
// No __syncthreads needed: each wave reads only its own LDS bias slots.

#define ROWS 4

typedef float v4f __attribute__((ext_vector_type(4)));

__global__ __launch_bounds__(256, 8) void relpos_fused_v4(
    const float* __restrict__ query,   // [32768, 64]
    const float* __restrict__ scores,  // [32768, 2048]
    const float* __restrict__ hemb,    // [31, 64]
    const float* __restrict__ wemb,    // [31, 64]
    const float* __restrict__ temb,    // [15, 64]
    float* __restrict__ out)           // [32768, 2048]
{
    __shared__ float biasH[ROWS][16];
    __shared__ float biasW[ROWS][16];  // read as v4f[4]
    __shared__ float biasT[ROWS][8];

    const int tid  = threadIdx.x;
    const int wv   = tid >> 6;             // wave id = local row
    const int lane = tid & 63;

    const int grow = blockIdx.x * ROWS + wv;  // global row [0, 32768)
    const int row  = grow & 2047;             // within (b,n)
    const int tt   = row >> 8;
    const int qh   = (row >> 4) & 15;
    const int qw   = row & 15;

    // --- Prelude: 40 dots for this wave's row (lanes 0..39) ---
    if (lane < 40) {
        const float* emb;
        int eidx;
        if (lane < 16)      { emb = hemb; eidx = qh - lane + 15; }
        else if (lane < 32) { emb = wemb; eidx = qw - (lane - 16) + 15; }
        else                { emb = temb; eidx = tt - (lane - 32) + 7; }
        const v4f* e4 = (const v4f*)(emb + eidx * 64);
        const v4f* q4 = (const v4f*)(query + (size_t)grow * 64);
        v4f a4 = (v4f)(0.f);
        #pragma unroll
        for (int k = 0; k < 16; ++k) {
            a4 += q4[k] * e4[k];
        }
        const float acc = (a4.x + a4.y) + (a4.z + a4.w);
        if (lane < 16)      biasH[wv][lane] = acc;
        else if (lane < 32) biasW[wv][lane - 16] = acc;
        else                biasT[wv][lane - 32] = acc;
    }
    // In-wave LDS write->read ordering: no barrier needed (wave reads only
    // slots its own wave wrote; compiler inserts the lgkmcnt wait).

    // --- Hoist per-lane biases into registers ---
    // Within row: element = i*256 + lane*4 + c  =>  kt=i, kh=(lane>>2)&15,
    // kw quad = lane&3.
    const float h  = biasH[wv][(lane >> 2) & 15];
    const v4f  w4  = ((const v4f*)biasW[wv])[lane & 3];
    const v4f  hw4 = w4 + h;
    float tv[8];
    #pragma unroll
    for (int i = 0; i < 8; ++i) tv[i] = biasT[wv][i];

    // --- Pure-VMEM stream: 8 x (load 16B) then 8 x (add, store 16B) ---
    const v4f* s4p = (const v4f*)scores + (size_t)grow * 512 + lane;
    v4f*       o4p = (v4f*)out          + (size_t)grow * 512 + lane;

    v4f s[8];
    #pragma unroll
    for (int i = 0; i < 8; ++i)
        s[i] = __builtin_nontemporal_load(&s4p[i * 64]);
    #pragma unroll
    for (int i = 0; i < 8; ++i) {
        v4f o = s[i] + hw4 + tv[i];
        __builtin_nontemporal_store(o, &o4p[i * 64]);
    }
}

extern "C" void kernel_launch(void* const* d_in, const int* in_sizes, int n_in,
                              void* d_out, int out_size, void* d_ws, size_t ws_size,
                              hipStream_t stream) {
    const float* query  = (const float*)d_in[0];
    const float* scores = (const float*)d_in[1];
    const float* hemb   = (const float*)d_in[2];
    const float* wemb   = (const float*)d_in[3];
    const float* temb   = (const float*)d_in[4];
    float* out = (float*)d_out;

    relpos_fused_v4<<<32768 / ROWS, 256, 0, stream>>>(
        query, scores, hemb, wemb, temb, out);
}